// Round 1
// baseline (4219.275 us; speedup 1.0000x reference)
//
#include <hip/hip_runtime.h>
#include <math.h>

#define DD 128
#define BE 16

__global__ __launch_bounds__(128) void zero128_kernel(float* p) { p[threadIdx.x] = 0.f; }

__global__ __launch_bounds__(256) void colsum_kernel(const float* __restrict__ x,
                                                     float* __restrict__ colsum, int N) {
  int col = threadIdx.x & 127;
  int part = (blockIdx.x * blockDim.x + threadIdx.x) >> 7;
  int nparts = (gridDim.x * blockDim.x) >> 7;
  float s = 0.f;
  for (int r = part; r < N; r += nparts) s += x[(size_t)r * DD + col];
  atomicAdd(&colsum[col], s);
}

__global__ __launch_bounds__(128) void glb_kernel(const float* __restrict__ colsum,
                                                  const float* __restrict__ glb_W,
                                                  const float* __restrict__ glb_b,
                                                  float* __restrict__ g, float invN) {
  __shared__ float m[DD];
  int j = threadIdx.x;
  m[j] = colsum[j] * invN;
  __syncthreads();
  float s = glb_b[j];
#pragma unroll 8
  for (int k = 0; k < DD; ++k) s = fmaf(m[k], glb_W[k * DD + j], s);
  g[j] = fmaxf(s, 0.f);
}

// Fused edge kernel: gather -> [msg|att] hidden GEMM -> msg GEMM2 + att dot ->
// sigmoid-weighted atomic scatter into agg.
__global__ __launch_bounds__(256) void edge_kernel(
    const float* __restrict__ h, const int* __restrict__ src, const int* __restrict__ dst,
    const float* __restrict__ msg_W1, const float* __restrict__ msg_b1,
    const float* __restrict__ msg_W2, const float* __restrict__ msg_b2,
    const float* __restrict__ att_W1, const float* __restrict__ att_b1,
    const float* __restrict__ att_W2, const float* __restrict__ att_b2,
    float* __restrict__ agg) {
  __shared__ float EF[BE * 256];   // 16 KB edge features [e][0:128]=h[src], [128:256]=h[dst]
  __shared__ float HID[BE * 256];  // 16 KB hidden: [e][0:128]=msg hid, [128:256]=att hid
  __shared__ float WT[16 * 256];   // 16 KB weight tile
  __shared__ float attw[DD];
  __shared__ float attb;

  const int tid = threadIdx.x;
  const int e0 = blockIdx.x * BE;

  if (tid < DD) attw[tid] = att_W2[tid];
  if (tid == 0) attb = att_b2[0];

  // stage EF (float4 gather)
  {
    const float4* h4 = reinterpret_cast<const float4*>(h);
    float4* EF4 = reinterpret_cast<float4*>(EF);
#pragma unroll
    for (int i = 0; i < 4; ++i) {
      int f = tid + 256 * i;  // 0..1023
      int e = f >> 6;         // 0..15
      int c4 = f & 63;        // 0..63 (float4 col)
      int node = (c4 < 32) ? src[e0 + e] : dst[e0 + e];
      EF4[e * 64 + c4] = h4[(size_t)node * 32 + (c4 & 31)];
    }
  }

  // ---- GEMM1: HID[16][256] = relu(EF @ [msg_W1 | att_W1] + b) ----
  // thread tile: 4 edges x 4 cols
  const int eg = (tid >> 6) * 4;  // wave-uniform
  const int cg = tid & 63;
  float acc[4][4];
#pragma unroll
  for (int j = 0; j < 4; ++j) {
    int col = cg * 4 + j;
    float bv = (col < DD) ? msg_b1[col] : att_b1[col - DD];
    acc[0][j] = bv; acc[1][j] = bv; acc[2][j] = bv; acc[3][j] = bv;
  }

  const float4* m14 = reinterpret_cast<const float4*>(msg_W1);
  const float4* a14 = reinterpret_cast<const float4*>(att_W1);
  float4* WT4 = reinterpret_cast<float4*>(WT);

  for (int k0 = 0; k0 < 256; k0 += 16) {
    __syncthreads();
#pragma unroll
    for (int i = 0; i < 4; ++i) {
      int f = tid + 256 * i;
      int kk = f >> 6;
      int c4 = f & 63;
      WT4[kk * 64 + c4] = (c4 < 32) ? m14[(k0 + kk) * 32 + c4] : a14[(k0 + kk) * 32 + (c4 - 32)];
    }
    __syncthreads();
#pragma unroll
    for (int kk = 0; kk < 16; ++kk) {
      float f0 = EF[(eg + 0) * 256 + k0 + kk];
      float f1 = EF[(eg + 1) * 256 + k0 + kk];
      float f2 = EF[(eg + 2) * 256 + k0 + kk];
      float f3 = EF[(eg + 3) * 256 + k0 + kk];
      float4 w = WT4[kk * 64 + cg];
      acc[0][0] = fmaf(f0, w.x, acc[0][0]); acc[0][1] = fmaf(f0, w.y, acc[0][1]);
      acc[0][2] = fmaf(f0, w.z, acc[0][2]); acc[0][3] = fmaf(f0, w.w, acc[0][3]);
      acc[1][0] = fmaf(f1, w.x, acc[1][0]); acc[1][1] = fmaf(f1, w.y, acc[1][1]);
      acc[1][2] = fmaf(f1, w.z, acc[1][2]); acc[1][3] = fmaf(f1, w.w, acc[1][3]);
      acc[2][0] = fmaf(f2, w.x, acc[2][0]); acc[2][1] = fmaf(f2, w.y, acc[2][1]);
      acc[2][2] = fmaf(f2, w.z, acc[2][2]); acc[2][3] = fmaf(f2, w.w, acc[2][3]);
      acc[3][0] = fmaf(f3, w.x, acc[3][0]); acc[3][1] = fmaf(f3, w.y, acc[3][1]);
      acc[3][2] = fmaf(f3, w.z, acc[3][2]); acc[3][3] = fmaf(f3, w.w, acc[3][3]);
    }
  }
  __syncthreads();
  {
    float4* HID4 = reinterpret_cast<float4*>(HID);
#pragma unroll
    for (int i = 0; i < 4; ++i) {
      float4 v;
      v.x = fmaxf(acc[i][0], 0.f);
      v.y = fmaxf(acc[i][1], 0.f);
      v.z = fmaxf(acc[i][2], 0.f);
      v.w = fmaxf(acc[i][3], 0.f);
      HID4[(eg + i) * 64 + cg] = v;
    }
  }
  __syncthreads();

  // ---- GEMM2: msg[16][128] = HID[:, 0:128] @ msg_W2 + b2 ----
  // thread tile: 2 edges x 4 cols
  const int eg2 = (tid >> 5) * 2;
  const int cg2 = tid & 31;
  float a2[2][4];
#pragma unroll
  for (int j = 0; j < 4; ++j) {
    float bv = msg_b2[cg2 * 4 + j];
    a2[0][j] = bv; a2[1][j] = bv;
  }
  const float4* m24 = reinterpret_cast<const float4*>(msg_W2);
  for (int j0 = 0; j0 < DD; j0 += 32) {
    __syncthreads();
#pragma unroll
    for (int i = 0; i < 4; ++i) {
      int f = tid + 256 * i;  // 0..1023 over 32x32 float4 tile
      int jj = f >> 5;
      int c4 = f & 31;
      WT4[jj * 32 + c4] = m24[(j0 + jj) * 32 + c4];
    }
    __syncthreads();
#pragma unroll
    for (int jj = 0; jj < 32; ++jj) {
      float h0 = HID[(eg2 + 0) * 256 + j0 + jj];
      float h1 = HID[(eg2 + 1) * 256 + j0 + jj];
      float4 w = WT4[jj * 32 + cg2];
      a2[0][0] = fmaf(h0, w.x, a2[0][0]); a2[0][1] = fmaf(h0, w.y, a2[0][1]);
      a2[0][2] = fmaf(h0, w.z, a2[0][2]); a2[0][3] = fmaf(h0, w.w, a2[0][3]);
      a2[1][0] = fmaf(h1, w.x, a2[1][0]); a2[1][1] = fmaf(h1, w.y, a2[1][1]);
      a2[1][2] = fmaf(h1, w.z, a2[1][2]); a2[1][3] = fmaf(h1, w.w, a2[1][3]);
    }
  }

  // attention scalar per edge (redundant per-thread dot; cheap)
  float s0 = attb, s1 = attb;
#pragma unroll 8
  for (int j = 0; j < DD; ++j) {
    float wv = attw[j];
    s0 = fmaf(HID[(eg2 + 0) * 256 + DD + j], wv, s0);
    s1 = fmaf(HID[(eg2 + 1) * 256 + DD + j], wv, s1);
  }
  float at0 = 1.f / (1.f + expf(-s0));
  float at1 = 1.f / (1.f + expf(-s1));

  int n0 = dst[e0 + eg2 + 0];
  int n1 = dst[e0 + eg2 + 1];
  float* p0 = agg + (size_t)n0 * DD + cg2 * 4;
  float* p1 = agg + (size_t)n1 * DD + cg2 * 4;
#pragma unroll
  for (int j = 0; j < 4; ++j) {
    atomicAdd(p0 + j, a2[0][j] * at0);
    atomicAdd(p1 + j, a2[1][j] * at1);
  }
}

// Node update: out = relu([h|agg] @ upd_W1 + b1) @ upd_W2 + b2 + h + g
__global__ __launch_bounds__(256) void node_kernel(
    const float* __restrict__ h, const float* __restrict__ agg,
    const float* __restrict__ upd_W1, const float* __restrict__ upd_b1,
    const float* __restrict__ upd_W2, const float* __restrict__ upd_b2,
    const float* __restrict__ g, float* __restrict__ out) {
  __shared__ float CF[BE * 256];   // [n][0:128]=h, [128:256]=agg
  __shared__ float HID[BE * DD];   // 8 KB
  __shared__ float WT[32 * DD];    // 16 KB
  __shared__ float gs[DD];

  const int tid = threadIdx.x;
  const int n0 = blockIdx.x * BE;
  if (tid < DD) gs[tid] = g[tid];

  {
    const float4* h4 = reinterpret_cast<const float4*>(h);
    const float4* agg4 = reinterpret_cast<const float4*>(agg);
    float4* CF4 = reinterpret_cast<float4*>(CF);
#pragma unroll
    for (int i = 0; i < 4; ++i) {
      int f = tid + 256 * i;
      int e = f >> 6;
      int c4 = f & 63;
      int node = n0 + e;
      CF4[e * 64 + c4] =
          (c4 < 32) ? h4[(size_t)node * 32 + c4] : agg4[(size_t)node * 32 + (c4 - 32)];
    }
  }

  const int eg = (tid >> 5) * 2;
  const int cg = tid & 31;
  float acc[2][4];
#pragma unroll
  for (int j = 0; j < 4; ++j) {
    float bv = upd_b1[cg * 4 + j];
    acc[0][j] = bv; acc[1][j] = bv;
  }
  const float4* w14 = reinterpret_cast<const float4*>(upd_W1);
  float4* WT4 = reinterpret_cast<float4*>(WT);
  for (int k0 = 0; k0 < 256; k0 += 32) {
    __syncthreads();
#pragma unroll
    for (int i = 0; i < 4; ++i) {
      int f = tid + 256 * i;
      int kk = f >> 5;
      int c4 = f & 31;
      WT4[kk * 32 + c4] = w14[(k0 + kk) * 32 + c4];
    }
    __syncthreads();
#pragma unroll
    for (int kk = 0; kk < 32; ++kk) {
      float f0 = CF[(eg + 0) * 256 + k0 + kk];
      float f1 = CF[(eg + 1) * 256 + k0 + kk];
      float4 w = WT4[kk * 32 + cg];
      acc[0][0] = fmaf(f0, w.x, acc[0][0]); acc[0][1] = fmaf(f0, w.y, acc[0][1]);
      acc[0][2] = fmaf(f0, w.z, acc[0][2]); acc[0][3] = fmaf(f0, w.w, acc[0][3]);
      acc[1][0] = fmaf(f1, w.x, acc[1][0]); acc[1][1] = fmaf(f1, w.y, acc[1][1]);
      acc[1][2] = fmaf(f1, w.z, acc[1][2]); acc[1][3] = fmaf(f1, w.w, acc[1][3]);
    }
  }
  __syncthreads();
  {
    float4* HID4 = reinterpret_cast<float4*>(HID);
    float4 v0, v1;
    v0.x = fmaxf(acc[0][0], 0.f); v0.y = fmaxf(acc[0][1], 0.f);
    v0.z = fmaxf(acc[0][2], 0.f); v0.w = fmaxf(acc[0][3], 0.f);
    v1.x = fmaxf(acc[1][0], 0.f); v1.y = fmaxf(acc[1][1], 0.f);
    v1.z = fmaxf(acc[1][2], 0.f); v1.w = fmaxf(acc[1][3], 0.f);
    HID4[(eg + 0) * 32 + cg] = v0;
    HID4[(eg + 1) * 32 + cg] = v1;
  }
  __syncthreads();

  float a2[2][4];
#pragma unroll
  for (int j = 0; j < 4; ++j) {
    float bv = upd_b2[cg * 4 + j];
    a2[0][j] = bv; a2[1][j] = bv;
  }
  const float4* w24 = reinterpret_cast<const float4*>(upd_W2);
  for (int j0 = 0; j0 < DD; j0 += 32) {
    __syncthreads();
#pragma unroll
    for (int i = 0; i < 4; ++i) {
      int f = tid + 256 * i;
      int jj = f >> 5;
      int c4 = f & 31;
      WT4[jj * 32 + c4] = w24[(j0 + jj) * 32 + c4];
    }
    __syncthreads();
#pragma unroll
    for (int jj = 0; jj < 32; ++jj) {
      float h0 = HID[(eg + 0) * DD + j0 + jj];
      float h1 = HID[(eg + 1) * DD + j0 + jj];
      float4 w = WT4[jj * 32 + cg];
      a2[0][0] = fmaf(h0, w.x, a2[0][0]); a2[0][1] = fmaf(h0, w.y, a2[0][1]);
      a2[0][2] = fmaf(h0, w.z, a2[0][2]); a2[0][3] = fmaf(h0, w.w, a2[0][3]);
      a2[1][0] = fmaf(h1, w.x, a2[1][0]); a2[1][1] = fmaf(h1, w.y, a2[1][1]);
      a2[1][2] = fmaf(h1, w.z, a2[1][2]); a2[1][3] = fmaf(h1, w.w, a2[1][3]);
    }
  }

  float4* out4 = reinterpret_cast<float4*>(out);
#pragma unroll
  for (int i = 0; i < 2; ++i) {
    int node = n0 + eg + i;
    float4 v;
    v.x = a2[i][0] + CF[(eg + i) * 256 + cg * 4 + 0] + gs[cg * 4 + 0];
    v.y = a2[i][1] + CF[(eg + i) * 256 + cg * 4 + 1] + gs[cg * 4 + 1];
    v.z = a2[i][2] + CF[(eg + i) * 256 + cg * 4 + 2] + gs[cg * 4 + 2];
    v.w = a2[i][3] + CF[(eg + i) * 256 + cg * 4 + 3] + gs[cg * 4 + 3];
    out4[(size_t)node * 32 + cg] = v;
  }
}

extern "C" void kernel_launch(void* const* d_in, const int* in_sizes, int n_in,
                              void* d_out, int out_size, void* d_ws, size_t ws_size,
                              hipStream_t stream) {
  const float* x = (const float*)d_in[0];
  const int* ei = (const int*)d_in[1];
  const float* msg_W1 = (const float*)d_in[2];
  const float* msg_b1 = (const float*)d_in[3];
  const float* msg_W2 = (const float*)d_in[4];
  const float* msg_b2 = (const float*)d_in[5];
  const float* upd_W1 = (const float*)d_in[6];
  const float* upd_b1 = (const float*)d_in[7];
  const float* upd_W2 = (const float*)d_in[8];
  const float* upd_b2 = (const float*)d_in[9];
  const float* att_W1 = (const float*)d_in[10];
  const float* att_b1 = (const float*)d_in[11];
  const float* att_W2 = (const float*)d_in[12];
  const float* att_b2 = (const float*)d_in[13];
  const float* glb_W = (const float*)d_in[14];
  const float* glb_b = (const float*)d_in[15];

  const int N = in_sizes[0] / DD;
  const int E = in_sizes[1] / 2;
  const int* src = ei;
  const int* dst = ei + E;

  float* out = (float*)d_out;
  float* agg = (float*)d_ws;                   // N*DD floats
  float* colsum = agg + (size_t)N * DD;        // DD floats
  float* g = colsum + DD;                      // DD floats

  zero128_kernel<<<1, 128, 0, stream>>>(colsum);
  colsum_kernel<<<256, 256, 0, stream>>>(x, colsum, N);
  glb_kernel<<<1, 128, 0, stream>>>(colsum, glb_W, glb_b, g, 1.0f / (float)N);

  for (int step = 0; step < 2; ++step) {
    const float* hptr = (step == 0) ? x : out;
    hipMemsetAsync(agg, 0, (size_t)N * DD * sizeof(float), stream);
    edge_kernel<<<E / BE, 256, 0, stream>>>(hptr, src, dst, msg_W1, msg_b1, msg_W2, msg_b2,
                                            att_W1, att_b1, att_W2, att_b2, agg);
    node_kernel<<<N / BE, 256, 0, stream>>>(hptr, agg, upd_W1, upd_b1, upd_W2, upd_b2, g, out);
  }
}

// Round 2
// 997.370 us; speedup vs baseline: 4.2304x; 4.2304x over previous
//
#include <hip/hip_runtime.h>
#include <math.h>

#define DD 128

typedef __attribute__((ext_vector_type(8))) short short8;   // 8 x bf16 bits
typedef __attribute__((ext_vector_type(4))) float f32x4;

__device__ inline short bf16hi(float x) {
  unsigned u = __float_as_uint(x);
  unsigned r = u + 0x7fffu + ((u >> 16) & 1u);  // RTNE
  return (short)(r >> 16);
}
__device__ inline float bf16tof(short h) {
  return __uint_as_float(((unsigned)(unsigned short)h) << 16);
}
__device__ inline void split2(float x, short& hi, short& lo) {
  hi = bf16hi(x);
  float rem = x - bf16tof(hi);
  lo = bf16hi(rem);
}

// ---------------- small helper kernels ----------------
__global__ __launch_bounds__(128) void zero128_kernel(float* p) { p[threadIdx.x] = 0.f; }

__global__ __launch_bounds__(256) void colsum_kernel(const float* __restrict__ x,
                                                     float* __restrict__ colsum, int N) {
  int col = threadIdx.x & 127;
  int part = (blockIdx.x * blockDim.x + threadIdx.x) >> 7;
  int nparts = (gridDim.x * blockDim.x) >> 7;
  float s = 0.f;
  for (int r = part; r < N; r += nparts) s += x[(size_t)r * DD + col];
  atomicAdd(&colsum[col], s);
}

__global__ __launch_bounds__(128) void glb_kernel(const float* __restrict__ colsum,
                                                  const float* __restrict__ glb_W,
                                                  const float* __restrict__ glb_b,
                                                  float* __restrict__ g, float invN) {
  __shared__ float m[DD];
  int j = threadIdx.x;
  m[j] = colsum[j] * invN;
  __syncthreads();
  float s = glb_b[j];
#pragma unroll 8
  for (int k = 0; k < DD; ++k) s = fmaf(m[k], glb_W[k * DD + j], s);
  g[j] = fmaxf(s, 0.f);
}

// Pre-split weights into transposed [col][k] bf16 hi/lo planes.
// W1T: 256 cols (0-127 msg, 128-255 att) x 256 k.  W2T: 128x128.
// U1T: 128 cols x 256 k.  U2T: 128x128.
__global__ __launch_bounds__(256) void conv_kernel(
    const float* __restrict__ msg_W1, const float* __restrict__ att_W1,
    const float* __restrict__ msg_W2, const float* __restrict__ upd_W1,
    const float* __restrict__ upd_W2,
    short* __restrict__ W1hiT, short* __restrict__ W1loT,
    short* __restrict__ W2hiT, short* __restrict__ W2loT,
    short* __restrict__ U1hiT, short* __restrict__ U1loT,
    short* __restrict__ U2hiT, short* __restrict__ U2loT) {
  int idx = blockIdx.x * 256 + threadIdx.x;  // 0 .. 131071
  float v; short hi, lo;
  if (idx < 65536) {
    int col = idx & 255, k = idx >> 8;
    v = (col < 128) ? msg_W1[k * 128 + col] : att_W1[k * 128 + (col - 128)];
    split2(v, hi, lo);
    W1hiT[col * 256 + k] = hi; W1loT[col * 256 + k] = lo;
  } else if (idx < 81920) {
    int j = idx - 65536; int col = j & 127, k = (j >> 7) & 127;
    v = msg_W2[k * 128 + col];
    split2(v, hi, lo);
    W2hiT[col * 128 + k] = hi; W2loT[col * 128 + k] = lo;
  } else if (idx < 114688) {
    int j = idx - 81920; int col = j & 127, k = j >> 7;  // k 0..255
    v = upd_W1[k * 128 + col];
    split2(v, hi, lo);
    U1hiT[col * 256 + k] = hi; U1loT[col * 256 + k] = lo;
  } else {
    int j = idx - 114688; int col = j & 127, k = (j >> 7) & 127;
    v = upd_W2[k * 128 + col];
    split2(v, hi, lo);
    U2hiT[col * 128 + k] = hi; U2loT[col * 128 + k] = lo;
  }
}

// ---------------- fused edge kernel (split-bf16 MFMA) ----------------
// Block: 256 thr = 4 waves, 64 edges (16 per wave).
// GEMM1: [64x256] @ W1[256x256] (cols 0-127 msg hidden, 128-255 att hidden)
// att dot in-register (shuffle reduce); msg hidden -> LDS (bf16 hi/lo) ->
// GEMM2: [64x128] @ W2[128x128]; sigmoid-weighted atomic scatter to agg.
// LDS plan (shorts):
//   [0,10240)      G1 WThi (256 cols x 40)   /  G2 WThi (128x40) in [0,5120)
//   [10240,20480)  G1 WTlo                   /  G2 WTlo in [5120,10240)
//   [10240,18944)  HIDlo (64 rows x 136)  -- written after G1 k-loop done
//   [20480,29184)  HIDhi (64 rows x 136)
__global__ __launch_bounds__(256, 2) void edge_mfma_kernel(
    const float* __restrict__ h, const int* __restrict__ src, const int* __restrict__ dst,
    const short* __restrict__ W1hiT, const short* __restrict__ W1loT,
    const short* __restrict__ W2hiT, const short* __restrict__ W2loT,
    const float* __restrict__ msg_b1, const float* __restrict__ att_b1,
    const float* __restrict__ msg_b2, const float* __restrict__ att_W2,
    const float* __restrict__ att_b2, float* __restrict__ agg, int E) {
  __shared__ short smem[29184];
  short* WT1hi = smem;                 // G1
  short* WT1lo = smem + 10240;
  short* WT2hi = smem;                 // G2 (re-staged)
  short* WT2lo = smem + 5120;
  short* HIDlo = smem + 10240;
  short* HIDhi = smem + 20480;

  const int tid = threadIdx.x;
  const int wave = tid >> 6;
  const int lane = tid & 63;
  const int m16 = lane & 15;
  const int q = lane >> 4;

  const int e0 = blockIdx.x * 64;
  const int eA = e0 + wave * 16 + m16;
  const int eAc = min(eA, E - 1);
  const int sA = src[eAc];
  const int dA = dst[eAc];

  float aw[8];
#pragma unroll
  for (int i = 0; i < 8; ++i) aw[i] = att_W2[i * 16 + m16];
  const float ab2 = att_b2[0];

  // --- A fragments: edge features split to bf16 hi/lo, MFMA A layout ---
  short8 a1h[8], a1l[8];
  {
    const float* rs = h + (size_t)sA * DD;
    const float* rd = h + (size_t)dA * DD;
#pragma unroll
    for (int t = 0; t < 8; ++t) {
      const float* base = ((t < 4) ? (rs + t * 32) : (rd + (t - 4) * 32)) + q * 8;
      float4 v0 = *(const float4*)(base);
      float4 v1 = *(const float4*)(base + 4);
      float f[8] = {v0.x, v0.y, v0.z, v0.w, v1.x, v1.y, v1.z, v1.w};
      short8 hh, ll;
#pragma unroll
      for (int j = 0; j < 8; ++j) { short hi, lo; split2(f[j], hi, lo); hh[j] = hi; ll[j] = lo; }
      a1h[t] = hh; a1l[t] = ll;
    }
  }

  // --- GEMM1 ---
  f32x4 acc[16];
#pragma unroll
  for (int n = 0; n < 16; ++n) {
    int col = n * 16 + m16;
    float b = (col < 128) ? msg_b1[col] : att_b1[col - 128];
    acc[n] = (f32x4){b, b, b, b};
  }

  for (int t = 0; t < 8; ++t) {
    __syncthreads();
#pragma unroll
    for (int r = 0; r < 8; ++r) {
      int idx = tid + 256 * r;          // 0..2047 chunks of short8
      int comp = idx >> 10;
      int cid = idx & 1023;
      int col = cid >> 2, sub = cid & 3;
      const short* gsrc = (comp ? W1loT : W1hiT) + col * 256 + t * 32 + sub * 8;
      short* ldst = (comp ? WT1lo : WT1hi) + col * 40 + sub * 8;
      *(short8*)ldst = *(const short8*)gsrc;
    }
    __syncthreads();
#pragma unroll
    for (int n = 0; n < 16; ++n) {
      const short* bp = WT1hi + (n * 16 + m16) * 40 + q * 8;
      short8 bh = *(const short8*)bp;
      short8 bl = *(const short8*)(bp + 10240);
      acc[n] = __builtin_amdgcn_mfma_f32_16x16x32_bf16(a1h[t], bh, acc[n], 0, 0, 0);
      acc[n] = __builtin_amdgcn_mfma_f32_16x16x32_bf16(a1l[t], bh, acc[n], 0, 0, 0);
      acc[n] = __builtin_amdgcn_mfma_f32_16x16x32_bf16(a1h[t], bl, acc[n], 0, 0, 0);
    }
  }

  // --- attention: dot(relu(att_hid), att_W2) via shuffle reduce ---
  float part0 = 0.f, part1 = 0.f, part2 = 0.f, part3 = 0.f;
#pragma unroll
  for (int i = 0; i < 8; ++i) {
    f32x4 a = acc[8 + i];
    part0 = fmaf(fmaxf(a[0], 0.f), aw[i], part0);
    part1 = fmaf(fmaxf(a[1], 0.f), aw[i], part1);
    part2 = fmaf(fmaxf(a[2], 0.f), aw[i], part2);
    part3 = fmaf(fmaxf(a[3], 0.f), aw[i], part3);
  }
#pragma unroll
  for (int off = 1; off < 16; off <<= 1) {
    part0 += __shfl_xor(part0, off);
    part1 += __shfl_xor(part1, off);
    part2 += __shfl_xor(part2, off);
    part3 += __shfl_xor(part3, off);
  }
  float attv[4];
  attv[0] = 1.f / (1.f + expf(-(part0 + ab2)));
  attv[1] = 1.f / (1.f + expf(-(part1 + ab2)));
  attv[2] = 1.f / (1.f + expf(-(part2 + ab2)));
  attv[3] = 1.f / (1.f + expf(-(part3 + ab2)));

  // --- msg hidden -> LDS (relu, split) ---
  __syncthreads();  // all WT1 reads done before HIDlo overlays WT1lo
#pragma unroll
  for (int n = 0; n < 8; ++n) {
    int col = n * 16 + m16;
#pragma unroll
    for (int r = 0; r < 4; ++r) {
      int row = wave * 16 + q * 4 + r;
      float v = fmaxf(acc[n][r], 0.f);
      short hi, lo; split2(v, hi, lo);
      HIDhi[row * 136 + col] = hi;
      HIDlo[row * 136 + col] = lo;
    }
  }
  __syncthreads();

  // --- GEMM2 A fragments ---
  short8 a2h[4], a2l[4];
  {
    int mrow = wave * 16 + m16;
#pragma unroll
    for (int t = 0; t < 4; ++t) {
      a2h[t] = *(const short8*)(HIDhi + mrow * 136 + t * 32 + q * 8);
      a2l[t] = *(const short8*)(HIDlo + mrow * 136 + t * 32 + q * 8);
    }
  }

  f32x4 acc2[8];
#pragma unroll
  for (int n = 0; n < 8; ++n) {
    float b = msg_b2[n * 16 + m16];
    acc2[n] = (f32x4){b, b, b, b};
  }

  for (int t = 0; t < 4; ++t) {
    __syncthreads();
#pragma unroll
    for (int r = 0; r < 4; ++r) {
      int idx = tid + 256 * r;          // 0..1023
      int comp = idx >> 9;
      int cid = idx & 511;
      int col = cid >> 2, sub = cid & 3;
      const short* gsrc = (comp ? W2loT : W2hiT) + col * 128 + t * 32 + sub * 8;
      short* ldst = (comp ? WT2lo : WT2hi) + col * 40 + sub * 8;
      *(short8*)ldst = *(const short8*)gsrc;
    }
    __syncthreads();
#pragma unroll
    for (int n = 0; n < 8; ++n) {
      const short* bp = WT2hi + (n * 16 + m16) * 40 + q * 8;
      short8 bh = *(const short8*)bp;
      short8 bl = *(const short8*)(bp + 5120);
      acc2[n] = __builtin_amdgcn_mfma_f32_16x16x32_bf16(a2h[t], bh, acc2[n], 0, 0, 0);
      acc2[n] = __builtin_amdgcn_mfma_f32_16x16x32_bf16(a2l[t], bh, acc2[n], 0, 0, 0);
      acc2[n] = __builtin_amdgcn_mfma_f32_16x16x32_bf16(a2h[t], bl, acc2[n], 0, 0, 0);
    }
  }

  // --- weighted atomic scatter ---
  int drow[4]; int evalid[4];
#pragma unroll
  for (int r = 0; r < 4; ++r) {
    int e = e0 + wave * 16 + q * 4 + r;
    evalid[r] = (e < E);
    drow[r] = dst[evalid[r] ? e : 0];
  }
#pragma unroll
  for (int n = 0; n < 8; ++n) {
    int col = n * 16 + m16;
#pragma unroll
    for (int r = 0; r < 4; ++r) {
      if (evalid[r]) atomicAdd(&agg[(size_t)drow[r] * DD + col], acc2[n][r] * attv[r]);
    }
  }
}

// ---------------- node update kernel (split-bf16 MFMA) ----------------
// Same structure; A rows = [h | agg] for 64 nodes; out = GEMM2 + h + g.
__global__ __launch_bounds__(256, 2) void node_mfma_kernel(
    const float* __restrict__ h, const float* __restrict__ agg,
    const short* __restrict__ U1hiT, const short* __restrict__ U1loT,
    const short* __restrict__ U2hiT, const short* __restrict__ U2loT,
    const float* __restrict__ upd_b1, const float* __restrict__ upd_b2,
    const float* __restrict__ g, float* __restrict__ out, int N) {
  __shared__ short smem[29184];
  short* WT1hi = smem;            // 128 cols x 40
  short* WT1lo = smem + 5120;
  short* HIDlo = smem + 10240;
  short* HIDhi = smem + 20480;

  const int tid = threadIdx.x;
  const int wave = tid >> 6;
  const int lane = tid & 63;
  const int m16 = lane & 15;
  const int q = lane >> 4;

  const int n0 = blockIdx.x * 64;
  const int nA = n0 + wave * 16 + m16;
  const int nAc = min(nA, N - 1);

  short8 a1h[8], a1l[8];
  {
    const float* rs = h + (size_t)nAc * DD;
    const float* rd = agg + (size_t)nAc * DD;
#pragma unroll
    for (int t = 0; t < 8; ++t) {
      const float* base = ((t < 4) ? (rs + t * 32) : (rd + (t - 4) * 32)) + q * 8;
      float4 v0 = *(const float4*)(base);
      float4 v1 = *(const float4*)(base + 4);
      float f[8] = {v0.x, v0.y, v0.z, v0.w, v1.x, v1.y, v1.z, v1.w};
      short8 hh, ll;
#pragma unroll
      for (int j = 0; j < 8; ++j) { short hi, lo; split2(f[j], hi, lo); hh[j] = hi; ll[j] = lo; }
      a1h[t] = hh; a1l[t] = ll;
    }
  }

  f32x4 acc[8];
#pragma unroll
  for (int n = 0; n < 8; ++n) {
    float b = upd_b1[n * 16 + m16];
    acc[n] = (f32x4){b, b, b, b};
  }

  for (int t = 0; t < 8; ++t) {
    __syncthreads();
#pragma unroll
    for (int r = 0; r < 4; ++r) {
      int idx = tid + 256 * r;          // 0..1023
      int comp = idx >> 9;
      int cid = idx & 511;
      int col = cid >> 2, sub = cid & 3;
      const short* gsrc = (comp ? U1loT : U1hiT) + col * 256 + t * 32 + sub * 8;
      short* ldst = (comp ? WT1lo : WT1hi) + col * 40 + sub * 8;
      *(short8*)ldst = *(const short8*)gsrc;
    }
    __syncthreads();
#pragma unroll
    for (int n = 0; n < 8; ++n) {
      const short* bp = WT1hi + (n * 16 + m16) * 40 + q * 8;
      short8 bh = *(const short8*)bp;
      short8 bl = *(const short8*)(bp + 5120);
      acc[n] = __builtin_amdgcn_mfma_f32_16x16x32_bf16(a1h[t], bh, acc[n], 0, 0, 0);
      acc[n] = __builtin_amdgcn_mfma_f32_16x16x32_bf16(a1l[t], bh, acc[n], 0, 0, 0);
      acc[n] = __builtin_amdgcn_mfma_f32_16x16x32_bf16(a1h[t], bl, acc[n], 0, 0, 0);
    }
  }

  __syncthreads();
#pragma unroll
  for (int n = 0; n < 8; ++n) {
    int col = n * 16 + m16;
#pragma unroll
    for (int r = 0; r < 4; ++r) {
      int row = wave * 16 + q * 4 + r;
      float v = fmaxf(acc[n][r], 0.f);
      short hi, lo; split2(v, hi, lo);
      HIDhi[row * 136 + col] = hi;
      HIDlo[row * 136 + col] = lo;
    }
  }
  __syncthreads();

  short8 a2h[4], a2l[4];
  {
    int mrow = wave * 16 + m16;
#pragma unroll
    for (int t = 0; t < 4; ++t) {
      a2h[t] = *(const short8*)(HIDhi + mrow * 136 + t * 32 + q * 8);
      a2l[t] = *(const short8*)(HIDlo + mrow * 136 + t * 32 + q * 8);
    }
  }

  f32x4 acc2[8];
#pragma unroll
  for (int n = 0; n < 8; ++n) {
    float b = upd_b2[n * 16 + m16];
    acc2[n] = (f32x4){b, b, b, b};
  }

  for (int t = 0; t < 4; ++t) {
    __syncthreads();
#pragma unroll
    for (int r = 0; r < 4; ++r) {
      int idx = tid + 256 * r;
      int comp = idx >> 9;
      int cid = idx & 511;
      int col = cid >> 2, sub = cid & 3;
      const short* gsrc = (comp ? U2loT : U2hiT) + col * 128 + t * 32 + sub * 8;
      short* ldst = (comp ? WT1lo : WT1hi) + col * 40 + sub * 8;
      *(short8*)ldst = *(const short8*)gsrc;
    }
    __syncthreads();
#pragma unroll
    for (int n = 0; n < 8; ++n) {
      const short* bp = WT1hi + (n * 16 + m16) * 40 + q * 8;
      short8 bh = *(const short8*)bp;
      short8 bl = *(const short8*)(bp + 5120);
      acc2[n] = __builtin_amdgcn_mfma_f32_16x16x32_bf16(a2h[t], bh, acc2[n], 0, 0, 0);
      acc2[n] = __builtin_amdgcn_mfma_f32_16x16x32_bf16(a2l[t], bh, acc2[n], 0, 0, 0);
      acc2[n] = __builtin_amdgcn_mfma_f32_16x16x32_bf16(a2h[t], bl, acc2[n], 0, 0, 0);
    }
  }

  // epilogue: out = acc2 + h + g
#pragma unroll
  for (int r = 0; r < 4; ++r) {
    int rowN = n0 + wave * 16 + q * 4 + r;
    if (rowN < N) {
#pragma unroll
      for (int n = 0; n < 8; ++n) {
        int col = n * 16 + m16;
        out[(size_t)rowN * DD + col] = acc2[n][r] + h[(size_t)rowN * DD + col] + g[col];
      }
    }
  }
}

extern "C" void kernel_launch(void* const* d_in, const int* in_sizes, int n_in,
                              void* d_out, int out_size, void* d_ws, size_t ws_size,
                              hipStream_t stream) {
  const float* x = (const float*)d_in[0];
  const int* ei = (const int*)d_in[1];
  const float* msg_W1 = (const float*)d_in[2];
  const float* msg_b1 = (const float*)d_in[3];
  const float* msg_W2 = (const float*)d_in[4];
  const float* msg_b2 = (const float*)d_in[5];
  const float* upd_W1 = (const float*)d_in[6];
  const float* upd_b1 = (const float*)d_in[7];
  const float* upd_W2 = (const float*)d_in[8];
  const float* upd_b2 = (const float*)d_in[9];
  const float* att_W1 = (const float*)d_in[10];
  const float* att_b1 = (const float*)d_in[11];
  const float* att_W2 = (const float*)d_in[12];
  const float* att_b2 = (const float*)d_in[13];
  const float* glb_W = (const float*)d_in[14];
  const float* glb_b = (const float*)d_in[15];

  const int N = in_sizes[0] / DD;
  const int E = in_sizes[1] / 2;
  const int* src = ei;
  const int* dst = ei + E;

  float* out = (float*)d_out;
  float* agg = (float*)d_ws;                 // N*128 f32
  float* colsum = agg + (size_t)N * DD;      // 128
  float* g = colsum + DD;                    // 128
  short* W1hiT = (short*)(g + DD);
  short* W1loT = W1hiT + 65536;
  short* W2hiT = W1loT + 65536;
  short* W2loT = W2hiT + 16384;
  short* U1hiT = W2loT + 16384;
  short* U1loT = U1hiT + 32768;
  short* U2hiT = U1loT + 32768;
  short* U2loT = U2hiT + 16384;

  conv_kernel<<<512, 256, 0, stream>>>(msg_W1, att_W1, msg_W2, upd_W1, upd_W2,
                                       W1hiT, W1loT, W2hiT, W2loT,
                                       U1hiT, U1loT, U2hiT, U2loT);
  zero128_kernel<<<1, 128, 0, stream>>>(colsum);
  colsum_kernel<<<256, 256, 0, stream>>>(x, colsum, N);
  glb_kernel<<<1, 128, 0, stream>>>(colsum, glb_W, glb_b, g, 1.0f / (float)N);

  const int egrid = (E + 63) / 64;
  const int ngrid = (N + 63) / 64;
  for (int step = 0; step < 2; ++step) {
    const float* hptr = (step == 0) ? x : out;
    hipMemsetAsync(agg, 0, (size_t)N * DD * sizeof(float), stream);
    edge_mfma_kernel<<<egrid, 256, 0, stream>>>(hptr, src, dst, W1hiT, W1loT, W2hiT, W2loT,
                                                msg_b1, att_b1, msg_b2, att_W2, att_b2, agg, E);
    node_mfma_kernel<<<ngrid, 256, 0, stream>>>(hptr, agg, U1hiT, U1loT, U2hiT, U2loT,
                                                upd_b1, upd_b2, g, out, N);
  }
}